// Round 7
// baseline (766.959 us; speedup 1.0000x reference)
//
#include <hip/hip_runtime.h>

#define N_NODES 100000
#define E_EDGES 3200000
#define F_IN    1433
#define K_PAD   1440   // w1t padded K (45*32)
#define NCH     98     // scan chunks of 1024
#define KPH     240    // k per LDS phase (6 phases)
#define BSTR    248    // Bs col stride in halves (124 dwords -> 2-way banks, free)

typedef _Float16 f16x4 __attribute__((ext_vector_type(4)));
typedef _Float16 f16x8 __attribute__((ext_vector_type(8)));
typedef float    f32x4 __attribute__((ext_vector_type(4)));

// ---------------- init: counts=0 + W1^T fp16 [64][K_PAD] zero-padded ----------------
__global__ void k_init(const float* __restrict__ w1, _Float16* __restrict__ w1t,
                       int* __restrict__ counts) {
    int i = blockIdx.x * 256 + threadIdx.x;
    if (i < N_NODES) counts[i] = 0;
    if (i < 64 * K_PAD) {
        int n = i / K_PAD, k = i - n * K_PAD;
        float v = (k < F_IN) ? w1[(size_t)k * 64 + n] : 0.f;
        w1t[i] = (_Float16)v;
    }
}

__global__ void k_hist(const int* __restrict__ dst, int* __restrict__ counts) {
    int idx = blockIdx.x * 256 + threadIdx.x;      // 3125*256*4 = 3.2M
    int4 d4 = ((const int4*)dst)[idx];
    atomicAdd(&counts[d4.x], 1);
    atomicAdd(&counts[d4.y], 1);
    atomicAdd(&counts[d4.z], 1);
    atomicAdd(&counts[d4.w], 1);
}

// ---------------- exclusive scan of counts (chunked) ----------------
__global__ void k_scan_a(const int* __restrict__ counts, int* __restrict__ csum) {
    __shared__ int sh[256];
    int b = blockIdx.x, t = threadIdx.x;
    int s = 0;
    for (int j = 0; j < 4; ++j) {
        int idx = b * 1024 + j * 256 + t;
        if (idx < N_NODES) s += counts[idx];
    }
    sh[t] = s; __syncthreads();
    for (int off = 128; off > 0; off >>= 1) {
        if (t < off) sh[t] += sh[t + off];
        __syncthreads();
    }
    if (t == 0) csum[b] = sh[0];
}

__global__ void k_scan_b(int* __restrict__ csum) {
    __shared__ int sh[128];
    int t = threadIdx.x;
    int v = (t < NCH) ? csum[t] : 0;
    sh[t] = v; __syncthreads();
    for (int off = 1; off < 128; off <<= 1) {
        int u = (t >= off) ? sh[t - off] : 0;
        __syncthreads();
        sh[t] += u;
        __syncthreads();
    }
    if (t < NCH) csum[t] = sh[t] - v;   // exclusive
}

__global__ void k_scan_c(const int* __restrict__ counts, const int* __restrict__ csum,
                         int* __restrict__ offsets, int* __restrict__ cursor) {
    __shared__ int sh[256];
    int b = blockIdx.x, t = threadIdx.x;
    int base = b * 1024 + t * 4;
    int c0 = (base + 0 < N_NODES) ? counts[base + 0] : 0;
    int c1 = (base + 1 < N_NODES) ? counts[base + 1] : 0;
    int c2 = (base + 2 < N_NODES) ? counts[base + 2] : 0;
    int c3 = (base + 3 < N_NODES) ? counts[base + 3] : 0;
    int tot = c0 + c1 + c2 + c3;
    sh[t] = tot; __syncthreads();
    for (int off = 1; off < 256; off <<= 1) {
        int v = (t >= off) ? sh[t - off] : 0;
        __syncthreads();
        sh[t] += v;
        __syncthreads();
    }
    int excl = sh[t] - tot;
    int o = csum[b] + excl;
    if (base + 0 < N_NODES) { offsets[base + 0] = o;            cursor[base + 0] = o; }
    if (base + 1 < N_NODES) { int q = o + c0;      offsets[base + 1] = q; cursor[base + 1] = q; }
    if (base + 2 < N_NODES) { int q = o + c0 + c1; offsets[base + 2] = q; cursor[base + 2] = q; }
    if (base + 3 < N_NODES) { int q = o + c0 + c1 + c2; offsets[base + 3] = q; cursor[base + 3] = q; }
}

__global__ void k_scatter(const int* __restrict__ src, const int* __restrict__ dst,
                          int* __restrict__ cursor, int* __restrict__ sorted_src) {
    int idx = blockIdx.x * 256 + threadIdx.x;
    int4 s4 = ((const int4*)src)[idx];
    int4 d4 = ((const int4*)dst)[idx];
    int p;
    p = atomicAdd(&cursor[d4.x], 1); sorted_src[p] = s4.x;
    p = atomicAdd(&cursor[d4.y], 1); sorted_src[p] = s4.y;
    p = atomicAdd(&cursor[d4.z], 1); sorted_src[p] = s4.z;
    p = atomicAdd(&cursor[d4.w], 1); sorted_src[p] = s4.w;
}

// ---------------- GEMM1 + fused att1: h1 = x @ W1, a_s1/a_d1 ----------------
// B in LDS, 6 K-phases of 240 -> 31.7 KB LDS -> 5 blocks/CU = 20 waves/CU.
// Inner loop: ONE vmcnt load (x float4 stream) + 4 ds_read_b64 + 4 MFMA per step.
__global__ __launch_bounds__(256) void k_gemm1(const float* __restrict__ x,
                                               const _Float16* __restrict__ w1t,
                                               const float* __restrict__ att_src1,
                                               const float* __restrict__ att_dst1,
                                               _Float16* __restrict__ h1,
                                               float* __restrict__ a_s1,
                                               float* __restrict__ a_d1) {
    __shared__ _Float16 Bs[64 * BSTR];   // 31744 B
    const int tid  = threadIdx.x;
    const int lane = tid & 63;
    const int wid  = blockIdx.x * 4 + (tid >> 6);
    const int l16  = lane & 15;
    const int l4   = lane >> 4;
    const int row0 = wid * 16;
    const bool active = (wid < 6250);    // 6250*16 = 100000 exact

    const float* ap = x + (size_t)(active ? (row0 + l16) : 0) * F_IN + l4 * 4;

    f32x4 acc[4] = {};
    for (int ph = 0; ph < 6; ++ph) {
        const int k0 = ph * KPH;
        __syncthreads();                 // previous phase's reads done before overwrite
        for (int i = tid; i < 1920; i += 256) {   // 64 cols x 30 f16x8 chunks
            int col = i / 30, rem = i - col * 30;
            *(f16x8*)(&Bs[col * BSTR + rem * 8]) =
                *(const f16x8*)(w1t + (size_t)col * K_PAD + k0 + rem * 8);
        }
        __syncthreads();
        if (active) {
            const float* app = ap + k0;
            const int nst = (ph == 5) ? 14 : 15;
            for (int st = 0; st < nst; ++st) {
                float4 av = *(const float4*)(app + st * 16);
                f16x4 a = { (_Float16)av.x, (_Float16)av.y,
                            (_Float16)av.z, (_Float16)av.w };
                #pragma unroll
                for (int t = 0; t < 4; ++t) {
                    f16x4 b = *(const f16x4*)(&Bs[(t * 16 + l16) * BSTR + st * 16 + l4 * 4]);
                    acc[t] = __builtin_amdgcn_mfma_f32_16x16x16f16(a, b, acc[t], 0, 0, 0);
                }
            }
            if (ph == 5) {               // tail step st=14: k = 1424+l4*4+i, guard >= 1433
                const int kb = 1424 + l4 * 4;
                f16x4 a;
                #pragma unroll
                for (int i = 0; i < 4; ++i)
                    a[i] = (kb + i < F_IN) ? (_Float16)app[14 * 16 + i] : (_Float16)0.f;
                #pragma unroll
                for (int t = 0; t < 4; ++t) {
                    f16x4 b = *(const f16x4*)(&Bs[(t * 16 + l16) * BSTR + 14 * 16 + l4 * 4]);
                    acc[t] = __builtin_amdgcn_mfma_f32_16x16x16f16(a, b, acc[t], 0, 0, 0);
                }
            }
        }
    }
    if (!active) return;

    // epilogue: h1 write + fused attention coefficients (reduce over 8 channels)
    #pragma unroll
    for (int t = 0; t < 4; ++t) {
        const int head = t * 2 + (l16 >> 3);
        const int ch   = l16 & 7;
        const float asc = att_src1[head * 8 + ch];
        const float adc = att_dst1[head * 8 + ch];
        #pragma unroll
        for (int j = 0; j < 4; ++j) {
            int r = row0 + l4 * 4 + j;     // C: col = lane&15, row = (lane>>4)*4 + reg
            h1[(size_t)r * 64 + t * 16 + l16] = (_Float16)acc[t][j];
            float ps = acc[t][j] * asc, pd = acc[t][j] * adc;
            ps += __shfl_xor(ps, 1); ps += __shfl_xor(ps, 2); ps += __shfl_xor(ps, 4);
            pd += __shfl_xor(pd, 1); pd += __shfl_xor(pd, 2); pd += __shfl_xor(pd, 4);
            if (ch == 0) {
                a_s1[r * 8 + head] = ps;
                a_d1[r * 8 + head] = pd;
            }
        }
    }
}

// ---------------- layer-1 aggregate (defer-max softmax) + ELU + layer-2 prep ----------------
// 1 node / wave; lane = es*8 + h (8 edge-slots x 8 heads). m seeded from e_self;
// rescale only when e > m+8 (rare) -> no per-edge dependent rescale chain.
__global__ __launch_bounds__(256) void k_agg1(
    const int* __restrict__ offsets, const int* __restrict__ counts,
    const int* __restrict__ sorted_src,
    const float* __restrict__ a_s1, const float* __restrict__ a_d1,
    const _Float16* __restrict__ h1, const float* __restrict__ b1,
    const float* __restrict__ w2, const float* __restrict__ att_src2,
    const float* __restrict__ att_dst2,
    _Float16* __restrict__ g, float* __restrict__ a_s2, float* __restrict__ a_d2) {
    const int lane = threadIdx.x & 63;
    const int wave = threadIdx.x >> 6;
    const int h    = lane & 7;
    const int es   = lane >> 3;
    const int n    = blockIdx.x * 4 + wave;     // 25000*4 = 100000 exact
    const int start = offsets[n];
    const int cnt   = counts[n];
    const float adn = a_d1[n * 8 + h];
    float et = a_s1[n * 8 + h] + adn;
    const float e_self = et > 0.f ? et : 0.2f * et;

    float m = e_self, denom = 0.f;
    float acc[8] = {0.f,0.f,0.f,0.f,0.f,0.f,0.f,0.f};
    if (es == 0) {                 // self-loop: exp(e_self - m) = 1
        denom = 1.f;
        f16x8 hv = *(const f16x8*)(h1 + (size_t)n * 64 + h * 8);
        #pragma unroll
        for (int c = 0; c < 8; ++c) acc[c] = (float)hv[c];
    }
    for (int i = es; i < cnt; i += 8) {
        int s = sorted_src[start + i];
        float e = a_s1[s * 8 + h] + adn;
        e = e > 0.f ? e : 0.2f * e;
        if (e > m + 8.f) {         // rare rescale
            float sc = __expf(m - e);
            denom *= sc;
            #pragma unroll
            for (int c = 0; c < 8; ++c) acc[c] *= sc;
            m = e;
        }
        float p = __expf(e - m);   // bounded by e^8
        f16x8 hv = *(const f16x8*)(h1 + (size_t)s * 64 + h * 8);
        denom += p;
        #pragma unroll
        for (int c = 0; c < 8; ++c) acc[c] += p * (float)hv[c];
    }
    // combine 8 edge-slots per head (xor 8,16,32); m may differ after rescales
    #pragma unroll
    for (int d = 8; d < 64; d <<= 1) {
        float mo = __shfl_xor(m, d);
        float dn = __shfl_xor(denom, d);
        float mn = fmaxf(m, mo);
        float sa = __expf(m - mn), sb = __expf(mo - mn);
        denom = denom * sa + dn * sb;
        #pragma unroll
        for (int c = 0; c < 8; ++c) {
            float ao = __shfl_xor(acc[c], d);
            acc[c] = acc[c] * sa + ao * sb;
        }
        m = mn;
    }
    float inv = 1.f / (denom + 1e-16f);
    float hc[8];
    #pragma unroll
    for (int c = 0; c < 8; ++c) {
        float v = acc[c] * inv;
        v += __shfl_xor(v, 1);
        v += __shfl_xor(v, 2);
        v += __shfl_xor(v, 4);                  // mean over heads
        float o = 0.125f * v + b1[c];
        hc[c] = o > 0.f ? o : expm1f(o);        // ELU
    }
    if (lane == 0) {
        float s2 = 0.f, d2 = 0.f;
        f16x8 gr;
        #pragma unroll
        for (int j = 0; j < 7; ++j) {
            float t = 0.f;
            #pragma unroll
            for (int c = 0; c < 8; ++c) t += hc[c] * w2[c * 7 + j];
            gr[j] = (_Float16)t;
            s2 += t * att_src2[j];
            d2 += t * att_dst2[j];
        }
        gr[7] = (_Float16)0.f;
        *(f16x8*)(g + (size_t)n * 8) = gr;
        a_s2[n] = s2;
        a_d2[n] = d2;
    }
}

// ---------------- layer-2 aggregate (defer-max) + log_softmax (8 lanes/node) ----------------
__global__ __launch_bounds__(256) void k_agg2(
    const int* __restrict__ offsets, const int* __restrict__ counts,
    const int* __restrict__ sorted_src,
    const float* __restrict__ a_s2, const float* __restrict__ a_d2,
    const _Float16* __restrict__ g, const float* __restrict__ b2,
    float* __restrict__ outp) {
    const int tid  = threadIdx.x;
    const int lane = tid & 63;
    const int wave = tid >> 6;
    const int grp  = lane >> 3;
    const int s    = lane & 7;
    const int n    = blockIdx.x * 32 + wave * 8 + grp;
    const int start = offsets[n];
    const int cnt   = counts[n];
    const float adn = a_d2[n];
    float et = a_s2[n] + adn;
    const float e_self = et > 0.f ? et : 0.2f * et;

    float m = e_self, denom = 0.f;
    float acc[8] = {0.f,0.f,0.f,0.f,0.f,0.f,0.f,0.f};
    if (s == 0) {
        denom = 1.f;
        f16x8 gv = *(const f16x8*)(g + (size_t)n * 8);
        #pragma unroll
        for (int c = 0; c < 8; ++c) acc[c] = (float)gv[c];
    }
    for (int i = s; i < cnt; i += 8) {
        int sc = sorted_src[start + i];
        float e = a_s2[sc] + adn;
        e = e > 0.f ? e : 0.2f * e;
        if (e > m + 8.f) {
            float scale = __expf(m - e);
            denom *= scale;
            #pragma unroll
            for (int c = 0; c < 8; ++c) acc[c] *= scale;
            m = e;
        }
        float p = __expf(e - m);
        f16x8 gv = *(const f16x8*)(g + (size_t)sc * 8);
        denom += p;
        #pragma unroll
        for (int c = 0; c < 8; ++c) acc[c] += p * (float)gv[c];
    }
    #pragma unroll
    for (int d = 1; d < 8; d <<= 1) {
        float mo = __shfl_xor(m, d, 8);
        float dn = __shfl_xor(denom, d, 8);
        float mn = fmaxf(m, mo);
        float sa = __expf(m - mn), sb = __expf(mo - mn);
        denom = denom * sa + dn * sb;
        #pragma unroll
        for (int c = 0; c < 8; ++c) {
            float ao = __shfl_xor(acc[c], d, 8);
            acc[c] = acc[c] * sa + ao * sb;
        }
        m = mn;
    }
    float inv = 1.f / (denom + 1e-16f);
    float o[7]; float mx = -1e30f;
    #pragma unroll
    for (int c = 0; c < 7; ++c) { o[c] = acc[c] * inv + b2[c]; mx = fmaxf(mx, o[c]); }
    float se = 0.f;
    #pragma unroll
    for (int c = 0; c < 7; ++c) se += __expf(o[c] - mx);
    float ls = mx + logf(se);
    if (s < 7) outp[n * 7 + s] = o[s] - ls;
}

extern "C" void kernel_launch(void* const* d_in, const int* in_sizes, int n_in,
                              void* d_out, int out_size, void* d_ws, size_t ws_size,
                              hipStream_t stream) {
    const float* x        = (const float*)d_in[0];
    const int*   ei       = (const int*)d_in[1];
    const float* W1       = (const float*)d_in[2];
    const float* att_src1 = (const float*)d_in[3];
    const float* att_dst1 = (const float*)d_in[4];
    const float* b1       = (const float*)d_in[5];
    const float* W2       = (const float*)d_in[6];
    const float* att_src2 = (const float*)d_in[7];
    const float* att_dst2 = (const float*)d_in[8];
    const float* b2       = (const float*)d_in[9];
    const int* src = ei;
    const int* dst = ei + E_EDGES;

    char* ws = (char*)d_ws;
    size_t off = 0;
    auto alloc = [&](size_t bytes) -> char* {
        char* p = ws + off;
        off = (off + bytes + 255) & ~(size_t)255;
        return p;
    };
    _Float16* h1         = (_Float16*)alloc((size_t)N_NODES * 64 * 2);
    float*    a_s1       = (float*)   alloc((size_t)N_NODES * 8 * 4);
    float*    a_d1       = (float*)   alloc((size_t)N_NODES * 8 * 4);
    _Float16* w1t        = (_Float16*)alloc((size_t)64 * K_PAD * 2);
    int*      counts     = (int*)     alloc((size_t)N_NODES * 4);
    int*      offsets    = (int*)     alloc((size_t)N_NODES * 4);
    int*      cursor     = (int*)     alloc((size_t)N_NODES * 4);
    int*      csum       = (int*)     alloc((size_t)NCH * 4);
    int*      sorted_src = (int*)     alloc((size_t)E_EDGES * 4);
    _Float16* gbuf       = (_Float16*)alloc((size_t)N_NODES * 8 * 2);
    float*    a_s2       = (float*)   alloc((size_t)N_NODES * 4);
    float*    a_d2       = (float*)   alloc((size_t)N_NODES * 4);
    float*    outp       = (float*)d_out;

    hipLaunchKernelGGL(k_init,    dim3(391),   dim3(256), 0, stream, W1, w1t, counts);
    hipLaunchKernelGGL(k_hist,    dim3(3125),  dim3(256), 0, stream, dst, counts);
    hipLaunchKernelGGL(k_scan_a,  dim3(NCH),   dim3(256), 0, stream, counts, csum);
    hipLaunchKernelGGL(k_scan_b,  dim3(1),     dim3(128), 0, stream, csum);
    hipLaunchKernelGGL(k_scan_c,  dim3(NCH),   dim3(256), 0, stream, counts, csum, offsets, cursor);
    hipLaunchKernelGGL(k_scatter, dim3(3125),  dim3(256), 0, stream, src, dst, cursor, sorted_src);
    hipLaunchKernelGGL(k_gemm1,   dim3(1563),  dim3(256), 0, stream, x, w1t, att_src1, att_dst1,
                       h1, a_s1, a_d1);
    hipLaunchKernelGGL(k_agg1,    dim3(25000), dim3(256), 0, stream, offsets, counts, sorted_src,
                       a_s1, a_d1, h1, b1, W2, att_src2, att_dst2, gbuf, a_s2, a_d2);
    hipLaunchKernelGGL(k_agg2,    dim3(3125),  dim3(256), 0, stream, offsets, counts, sorted_src,
                       a_s2, a_d2, gbuf, b2, outp);
}

// Round 8
// 735.804 us; speedup vs baseline: 1.0423x; 1.0423x over previous
//
#include <hip/hip_runtime.h>

#define N_NODES 100000
#define E_EDGES 3200000
#define F_IN    1433
#define K_PAD   1440   // w1t padded K (45*32)
#define NCH     98     // scan chunks of 1024
#define KPH     240    // k per LDS phase (6 phases)
#define BSTR    248    // Bs col stride in halves

typedef _Float16 f16x4 __attribute__((ext_vector_type(4)));
typedef _Float16 f16x8 __attribute__((ext_vector_type(8)));
typedef float    f32x4 __attribute__((ext_vector_type(4)));

// ---------------- init: counts=0 + W1^T fp16 [64][K_PAD] zero-padded ----------------
__global__ void k_init(const float* __restrict__ w1, _Float16* __restrict__ w1t,
                       int* __restrict__ counts) {
    int i = blockIdx.x * 256 + threadIdx.x;
    if (i < N_NODES) counts[i] = 0;
    if (i < 64 * K_PAD) {
        int n = i / K_PAD, k = i - n * K_PAD;
        float v = (k < F_IN) ? w1[(size_t)k * 64 + n] : 0.f;
        w1t[i] = (_Float16)v;
    }
}

__global__ void k_hist(const int* __restrict__ dst, int* __restrict__ counts) {
    int idx = blockIdx.x * 256 + threadIdx.x;      // 3125*256*4 = 3.2M
    int4 d4 = ((const int4*)dst)[idx];
    atomicAdd(&counts[d4.x], 1);
    atomicAdd(&counts[d4.y], 1);
    atomicAdd(&counts[d4.z], 1);
    atomicAdd(&counts[d4.w], 1);
}

// ---------------- exclusive scan of counts (chunked) ----------------
__global__ void k_scan_a(const int* __restrict__ counts, int* __restrict__ csum) {
    __shared__ int sh[256];
    int b = blockIdx.x, t = threadIdx.x;
    int s = 0;
    for (int j = 0; j < 4; ++j) {
        int idx = b * 1024 + j * 256 + t;
        if (idx < N_NODES) s += counts[idx];
    }
    sh[t] = s; __syncthreads();
    for (int off = 128; off > 0; off >>= 1) {
        if (t < off) sh[t] += sh[t + off];
        __syncthreads();
    }
    if (t == 0) csum[b] = sh[0];
}

__global__ void k_scan_b(int* __restrict__ csum) {
    __shared__ int sh[128];
    int t = threadIdx.x;
    int v = (t < NCH) ? csum[t] : 0;
    sh[t] = v; __syncthreads();
    for (int off = 1; off < 128; off <<= 1) {
        int u = (t >= off) ? sh[t - off] : 0;
        __syncthreads();
        sh[t] += u;
        __syncthreads();
    }
    if (t < NCH) csum[t] = sh[t] - v;   // exclusive
}

__global__ void k_scan_c(const int* __restrict__ counts, const int* __restrict__ csum,
                         int* __restrict__ offsets, int* __restrict__ cursor) {
    __shared__ int sh[256];
    int b = blockIdx.x, t = threadIdx.x;
    int base = b * 1024 + t * 4;
    int c0 = (base + 0 < N_NODES) ? counts[base + 0] : 0;
    int c1 = (base + 1 < N_NODES) ? counts[base + 1] : 0;
    int c2 = (base + 2 < N_NODES) ? counts[base + 2] : 0;
    int c3 = (base + 3 < N_NODES) ? counts[base + 3] : 0;
    int tot = c0 + c1 + c2 + c3;
    sh[t] = tot; __syncthreads();
    for (int off = 1; off < 256; off <<= 1) {
        int v = (t >= off) ? sh[t - off] : 0;
        __syncthreads();
        sh[t] += v;
        __syncthreads();
    }
    int excl = sh[t] - tot;
    int o = csum[b] + excl;
    if (base + 0 < N_NODES) { offsets[base + 0] = o;            cursor[base + 0] = o; }
    if (base + 1 < N_NODES) { int q = o + c0;      offsets[base + 1] = q; cursor[base + 1] = q; }
    if (base + 2 < N_NODES) { int q = o + c0 + c1; offsets[base + 2] = q; cursor[base + 2] = q; }
    if (base + 3 < N_NODES) { int q = o + c0 + c1 + c2; offsets[base + 3] = q; cursor[base + 3] = q; }
}

__global__ void k_scatter(const int* __restrict__ src, const int* __restrict__ dst,
                          int* __restrict__ cursor, int* __restrict__ sorted_src) {
    int idx = blockIdx.x * 256 + threadIdx.x;
    int4 s4 = ((const int4*)src)[idx];
    int4 d4 = ((const int4*)dst)[idx];
    int p;
    p = atomicAdd(&cursor[d4.x], 1); sorted_src[p] = s4.x;
    p = atomicAdd(&cursor[d4.y], 1); sorted_src[p] = s4.y;
    p = atomicAdd(&cursor[d4.z], 1); sorted_src[p] = s4.z;
    p = atomicAdd(&cursor[d4.w], 1); sorted_src[p] = s4.w;
}

// ---------------- GEMM1 + fused att1: h1 = x @ W1, a_s1/a_d1 ----------------
// B in LDS (6 K-phases of 240, 31.7 KB -> 5 blocks/CU). A-loads batched 5-deep
// for MLP (5 KB/wave in flight). No K tail-guard: w1t zero-pad masks k>=1433.
__global__ __launch_bounds__(256) void k_gemm1(const float* __restrict__ x,
                                               const _Float16* __restrict__ w1t,
                                               const float* __restrict__ att_src1,
                                               const float* __restrict__ att_dst1,
                                               _Float16* __restrict__ h1,
                                               float* __restrict__ a_s1,
                                               float* __restrict__ a_d1) {
    __shared__ _Float16 Bs[64 * BSTR];   // 31744 B
    const int tid  = threadIdx.x;
    const int lane = tid & 63;
    const int wid  = blockIdx.x * 4 + (tid >> 6);
    const int l16  = lane & 15;
    const int l4   = lane >> 4;
    const int row0 = wid * 16;
    const bool active = (wid < 6250);    // 6250*16 = 100000 exact

    const float* ap = x + (size_t)(active ? (row0 + l16) : 0) * F_IN + l4 * 4;

    f32x4 acc[4] = {};
    for (int ph = 0; ph < 6; ++ph) {
        const int k0 = ph * KPH;
        __syncthreads();                 // previous phase's reads done before overwrite
        for (int i = tid; i < 1920; i += 256) {   // 64 cols x 30 f16x8 chunks
            int col = i / 30, rem = i - col * 30;
            *(f16x8*)(&Bs[col * BSTR + rem * 8]) =
                *(const f16x8*)(w1t + (size_t)col * K_PAD + k0 + rem * 8);
        }
        __syncthreads();
        if (active) {
            const float* app = ap + k0;
            #pragma unroll
            for (int blk = 0; blk < 3; ++blk) {      // 3 batches x 5 steps
                float4 av[5];
                #pragma unroll
                for (int u = 0; u < 5; ++u)
                    av[u] = *(const float4*)(app + (blk * 5 + u) * 16);
                #pragma unroll
                for (int u = 0; u < 5; ++u) {
                    const int st = blk * 5 + u;
                    f16x4 a = { (_Float16)av[u].x, (_Float16)av[u].y,
                                (_Float16)av[u].z, (_Float16)av[u].w };
                    #pragma unroll
                    for (int t = 0; t < 4; ++t) {
                        f16x4 b = *(const f16x4*)(&Bs[(t * 16 + l16) * BSTR + st * 16 + l4 * 4]);
                        acc[t] = __builtin_amdgcn_mfma_f32_16x16x16f16(a, b, acc[t], 0, 0, 0);
                    }
                }
            }
        }
    }
    if (!active) return;

    // epilogue: h1 write + fused attention coefficients (reduce over 8 channels)
    #pragma unroll
    for (int t = 0; t < 4; ++t) {
        const int head = t * 2 + (l16 >> 3);
        const int ch   = l16 & 7;
        const float asc = att_src1[head * 8 + ch];
        const float adc = att_dst1[head * 8 + ch];
        #pragma unroll
        for (int j = 0; j < 4; ++j) {
            int r = row0 + l4 * 4 + j;     // C: col = lane&15, row = (lane>>4)*4 + reg
            h1[(size_t)r * 64 + t * 16 + l16] = (_Float16)acc[t][j];
            float ps = acc[t][j] * asc, pd = acc[t][j] * adc;
            ps += __shfl_xor(ps, 1); ps += __shfl_xor(ps, 2); ps += __shfl_xor(ps, 4);
            pd += __shfl_xor(pd, 1); pd += __shfl_xor(pd, 2); pd += __shfl_xor(pd, 4);
            if (ch == 0) {
                a_s1[r * 8 + head] = ps;
                a_d1[r * 8 + head] = pd;
            }
        }
    }
}

// ---------------- layer-1 aggregate (defer-max + prefetch pipeline) ----------------
// 1 node / wave; lane = es*8 + h. Next edge's {idx, a_s, h1} loads issue before
// current edge's math -> gather latency overlaps compute.
__global__ __launch_bounds__(256) void k_agg1(
    const int* __restrict__ offsets, const int* __restrict__ counts,
    const int* __restrict__ sorted_src,
    const float* __restrict__ a_s1, const float* __restrict__ a_d1,
    const _Float16* __restrict__ h1, const float* __restrict__ b1,
    const float* __restrict__ w2, const float* __restrict__ att_src2,
    const float* __restrict__ att_dst2,
    _Float16* __restrict__ g, float* __restrict__ a_s2, float* __restrict__ a_d2) {
    const int lane = threadIdx.x & 63;
    const int wave = threadIdx.x >> 6;
    const int h    = lane & 7;
    const int es   = lane >> 3;
    const int n    = blockIdx.x * 4 + wave;     // 25000*4 = 100000 exact
    const int start = offsets[n];
    const int cnt   = counts[n];
    const float adn = a_d1[n * 8 + h];
    float et = a_s1[n * 8 + h] + adn;
    const float e_self = et > 0.f ? et : 0.2f * et;

    float m = e_self, denom = 0.f;
    float acc[8] = {0.f,0.f,0.f,0.f,0.f,0.f,0.f,0.f};
    if (es == 0) {                 // self-loop: exp(e_self - m) = 1
        denom = 1.f;
        f16x8 hv0 = *(const f16x8*)(h1 + (size_t)n * 64 + h * 8);
        #pragma unroll
        for (int c = 0; c < 8; ++c) acc[c] = (float)hv0[c];
    }
    int i = es;
    if (i < cnt) {
        int s = sorted_src[start + i];
        float av = a_s1[s * 8 + h];
        f16x8 hv = *(const f16x8*)(h1 + (size_t)s * 64 + h * 8);
        for (;;) {
            const int inx = i + 8;
            const bool more = inx < cnt;
            int   sn = sorted_src[start + (more ? inx : i)];
            float an = a_s1[sn * 8 + h];
            f16x8 hn = *(const f16x8*)(h1 + (size_t)sn * 64 + h * 8);
            float e = av + adn;
            e = e > 0.f ? e : 0.2f * e;
            if (e > m + 8.f) {     // rare rescale
                float sc = __expf(m - e);
                denom *= sc;
                #pragma unroll
                for (int c = 0; c < 8; ++c) acc[c] *= sc;
                m = e;
            }
            float p = __expf(e - m);
            denom += p;
            #pragma unroll
            for (int c = 0; c < 8; ++c) acc[c] += p * (float)hv[c];
            if (!more) break;
            i = inx; av = an; hv = hn;
        }
    }
    // combine 8 edge-slots per head (xor 8,16,32); m may differ after rescales
    #pragma unroll
    for (int d = 8; d < 64; d <<= 1) {
        float mo = __shfl_xor(m, d);
        float dn = __shfl_xor(denom, d);
        float mn = fmaxf(m, mo);
        float sa = __expf(m - mn), sb = __expf(mo - mn);
        denom = denom * sa + dn * sb;
        #pragma unroll
        for (int c = 0; c < 8; ++c) {
            float ao = __shfl_xor(acc[c], d);
            acc[c] = acc[c] * sa + ao * sb;
        }
        m = mn;
    }
    float inv = 1.f / (denom + 1e-16f);
    float hc[8];
    #pragma unroll
    for (int c = 0; c < 8; ++c) {
        float v = acc[c] * inv;
        v += __shfl_xor(v, 1);
        v += __shfl_xor(v, 2);
        v += __shfl_xor(v, 4);                  // mean over heads
        float o = 0.125f * v + b1[c];
        hc[c] = o > 0.f ? o : expm1f(o);        // ELU
    }
    if (lane == 0) {
        float s2 = 0.f, d2 = 0.f;
        f16x8 gr;
        #pragma unroll
        for (int j = 0; j < 7; ++j) {
            float t = 0.f;
            #pragma unroll
            for (int c = 0; c < 8; ++c) t += hc[c] * w2[c * 7 + j];
            gr[j] = (_Float16)t;
            s2 += t * att_src2[j];
            d2 += t * att_dst2[j];
        }
        gr[7] = (_Float16)0.f;
        *(f16x8*)(g + (size_t)n * 8) = gr;
        a_s2[n] = s2;
        a_d2[n] = d2;
    }
}

// ---------------- layer-2 aggregate (defer-max + prefetch) + log_softmax ----------------
__global__ __launch_bounds__(256) void k_agg2(
    const int* __restrict__ offsets, const int* __restrict__ counts,
    const int* __restrict__ sorted_src,
    const float* __restrict__ a_s2, const float* __restrict__ a_d2,
    const _Float16* __restrict__ g, const float* __restrict__ b2,
    float* __restrict__ outp) {
    const int tid  = threadIdx.x;
    const int lane = tid & 63;
    const int wave = tid >> 6;
    const int grp  = lane >> 3;
    const int s    = lane & 7;
    const int n    = blockIdx.x * 32 + wave * 8 + grp;
    const int start = offsets[n];
    const int cnt   = counts[n];
    const float adn = a_d2[n];
    float et = a_s2[n] + adn;
    const float e_self = et > 0.f ? et : 0.2f * et;

    float m = e_self, denom = 0.f;
    float acc[8] = {0.f,0.f,0.f,0.f,0.f,0.f,0.f,0.f};
    if (s == 0) {
        denom = 1.f;
        f16x8 gv0 = *(const f16x8*)(g + (size_t)n * 8);
        #pragma unroll
        for (int c = 0; c < 8; ++c) acc[c] = (float)gv0[c];
    }
    int i = s;
    if (i < cnt) {
        int sc = sorted_src[start + i];
        float av = a_s2[sc];
        f16x8 gv = *(const f16x8*)(g + (size_t)sc * 8);
        for (;;) {
            const int inx = i + 8;
            const bool more = inx < cnt;
            int   sn = sorted_src[start + (more ? inx : i)];
            float an = a_s2[sn];
            f16x8 gn = *(const f16x8*)(g + (size_t)sn * 8);
            float e = av + adn;
            e = e > 0.f ? e : 0.2f * e;
            if (e > m + 8.f) {
                float scl = __expf(m - e);
                denom *= scl;
                #pragma unroll
                for (int c = 0; c < 8; ++c) acc[c] *= scl;
                m = e;
            }
            float p = __expf(e - m);
            denom += p;
            #pragma unroll
            for (int c = 0; c < 8; ++c) acc[c] += p * (float)gv[c];
            if (!more) break;
            i = inx; av = an; gv = gn;
        }
    }
    #pragma unroll
    for (int d = 1; d < 8; d <<= 1) {
        float mo = __shfl_xor(m, d, 8);
        float dn = __shfl_xor(denom, d, 8);
        float mn = fmaxf(m, mo);
        float sa = __expf(m - mn), sb = __expf(mo - mn);
        denom = denom * sa + dn * sb;
        #pragma unroll
        for (int c = 0; c < 8; ++c) {
            float ao = __shfl_xor(acc[c], d, 8);
            acc[c] = acc[c] * sa + ao * sb;
        }
        m = mn;
    }
    float inv = 1.f / (denom + 1e-16f);
    float o[7]; float mx = -1e30f;
    #pragma unroll
    for (int c = 0; c < 7; ++c) { o[c] = acc[c] * inv + b2[c]; mx = fmaxf(mx, o[c]); }
    float se = 0.f;
    #pragma unroll
    for (int c = 0; c < 7; ++c) se += __expf(o[c] - mx);
    float ls = mx + logf(se);
    if (s < 7) outp[n * 7 + s] = o[s] - ls;
}

extern "C" void kernel_launch(void* const* d_in, const int* in_sizes, int n_in,
                              void* d_out, int out_size, void* d_ws, size_t ws_size,
                              hipStream_t stream) {
    const float* x        = (const float*)d_in[0];
    const int*   ei       = (const int*)d_in[1];
    const float* W1       = (const float*)d_in[2];
    const float* att_src1 = (const float*)d_in[3];
    const float* att_dst1 = (const float*)d_in[4];
    const float* b1       = (const float*)d_in[5];
    const float* W2       = (const float*)d_in[6];
    const float* att_src2 = (const float*)d_in[7];
    const float* att_dst2 = (const float*)d_in[8];
    const float* b2       = (const float*)d_in[9];
    const int* src = ei;
    const int* dst = ei + E_EDGES;

    char* ws = (char*)d_ws;
    size_t off = 0;
    auto alloc = [&](size_t bytes) -> char* {
        char* p = ws + off;
        off = (off + bytes + 255) & ~(size_t)255;
        return p;
    };
    _Float16* h1         = (_Float16*)alloc((size_t)N_NODES * 64 * 2);
    float*    a_s1       = (float*)   alloc((size_t)N_NODES * 8 * 4);
    float*    a_d1       = (float*)   alloc((size_t)N_NODES * 8 * 4);
    _Float16* w1t        = (_Float16*)alloc((size_t)64 * K_PAD * 2);
    int*      counts     = (int*)     alloc((size_t)N_NODES * 4);
    int*      offsets    = (int*)     alloc((size_t)N_NODES * 4);
    int*      cursor     = (int*)     alloc((size_t)N_NODES * 4);
    int*      csum       = (int*)     alloc((size_t)NCH * 4);
    int*      sorted_src = (int*)     alloc((size_t)(E_EDGES + 32) * 4);
    _Float16* gbuf       = (_Float16*)alloc((size_t)N_NODES * 8 * 2);
    float*    a_s2       = (float*)   alloc((size_t)N_NODES * 4);
    float*    a_d2       = (float*)   alloc((size_t)N_NODES * 4);
    float*    outp       = (float*)d_out;

    hipLaunchKernelGGL(k_init,    dim3(391),   dim3(256), 0, stream, W1, w1t, counts);
    hipLaunchKernelGGL(k_hist,    dim3(3125),  dim3(256), 0, stream, dst, counts);
    hipLaunchKernelGGL(k_scan_a,  dim3(NCH),   dim3(256), 0, stream, counts, csum);
    hipLaunchKernelGGL(k_scan_b,  dim3(1),     dim3(128), 0, stream, csum);
    hipLaunchKernelGGL(k_scan_c,  dim3(NCH),   dim3(256), 0, stream, counts, csum, offsets, cursor);
    hipLaunchKernelGGL(k_scatter, dim3(3125),  dim3(256), 0, stream, src, dst, cursor, sorted_src);
    hipLaunchKernelGGL(k_gemm1,   dim3(1563),  dim3(256), 0, stream, x, w1t, att_src1, att_dst1,
                       h1, a_s1, a_d1);
    hipLaunchKernelGGL(k_agg1,    dim3(25000), dim3(256), 0, stream, offsets, counts, sorted_src,
                       a_s1, a_d1, h1, b1, W2, att_src2, att_dst2, gbuf, a_s2, a_d2);
    hipLaunchKernelGGL(k_agg2,    dim3(3125),  dim3(256), 0, stream, offsets, counts, sorted_src,
                       a_s2, a_d2, gbuf, b2, outp);
}